// Round 1
// baseline (218.579 us; speedup 1.0000x reference)
//
#include <hip/hip_runtime.h>
#include <math.h>

// CrossAttention: B=2, Sq=Sk=2048, H=16, Hkv=4, D=64, fp32 in/out.
// Flash-style online softmax with bf16 MFMA 16x16x32.
// NEG=-10000 masking is FINITE: tail keys (score==NEG exactly) are folded in
// analytically via w = exp(NEG - m_final): O += w * sum_tail(V), l += w * n_tail.
// w underflows to 0 for normal rows, is exact for fully-padded-prefix rows.

typedef __bf16 bf16x8 __attribute__((ext_vector_type(8)));
typedef float floatx4 __attribute__((ext_vector_type(4)));

#define B_ 2
#define SQ 2048
#define SK 2048
#define H_ 16
#define HKV 4
#define D_ 64
#define QT 128   // q rows per block
#define KT 64    // keys per k-tile
#define PADLD 72 // LDS leading dim (bf16 elems): 144B rows -> 2-way-max bank aliasing
#define NEGV (-10000.0f)

__global__ __launch_bounds__(256, 2)
void attn_kernel(const float* __restrict__ q,
                 const float* __restrict__ kv,
                 const int* __restrict__ mask,
                 float* __restrict__ out)
{
    __shared__ alignas(16) __bf16 Kt[KT][PADLD];     // K tile [key][d]
    __shared__ alignas(16) __bf16 Vt[D_][PADLD];     // V tile transposed [d][key]
    __shared__ alignas(16) __bf16 Pl[4][32][PADLD];  // per-wave P [qrow][key]
    __shared__ float padf[KT];
    __shared__ float vtail_red[4][D_];

    const int tid  = threadIdx.x;
    const int wave = tid >> 6;
    const int lane = tid & 63;
    const int col  = lane & 15;
    const int quad = lane >> 4;

    const int qt  = blockIdx.x;   // 0..15
    const int bh  = blockIdx.y;   // 0..31
    const int b   = bh >> 4;
    const int h   = bh & 15;
    const int hkv = h >> 2;

    const int q0 = qt * QT;
    const int qw = q0 + wave * 32;   // this wave's first q row

    // ---- Q fragments, pre-scaled by 1/sqrt(D); A-layout m=lane&15, k=quad*8+j ----
    const float scale = 0.125f;
    bf16x8 aq[2][2];
#pragma unroll
    for (int qi = 0; qi < 2; ++qi) {
        int row = qw + qi * 16 + col;
        const float* qp = q + (((size_t)b * SQ + row) * H_ + h) * D_ + quad * 8;
#pragma unroll
        for (int kc = 0; kc < 2; ++kc) {
            const float* p = qp + kc * 32;
#pragma unroll
            for (int j = 0; j < 8; ++j) aq[qi][kc][j] = (__bf16)(p[j] * scale);
        }
    }

    // ---- tail V sum: sum_{s in [q0+QT, SK)} v[b][s][hkv][d] ----
    {
        float acc = 0.f;
        const int dloc = tid & 63, rg = tid >> 6;
        for (int s = q0 + QT + rg; s < SK; s += 4)
            acc += kv[((((size_t)b * SK + s) * 2 + 1) * HKV + hkv) * D_ + dloc];
        vtail_red[rg][dloc] = acc;
    }
    __syncthreads();
    float vtail[4];
#pragma unroll
    for (int dj = 0; dj < 4; ++dj) {
        int d = dj * 16 + col;
        vtail[dj] = vtail_red[0][d] + vtail_red[1][d] + vtail_red[2][d] + vtail_red[3][d];
    }

    // ---- online-softmax state ----
    float m_s[2][4], l_s[2][4];
    floatx4 o[2][4];
#pragma unroll
    for (int qi = 0; qi < 2; ++qi)
#pragma unroll
        for (int r = 0; r < 4; ++r) { m_s[qi][r] = -1e30f; l_s[qi][r] = 0.f; }
#pragma unroll
    for (int qi = 0; qi < 2; ++qi)
#pragma unroll
        for (int dj = 0; dj < 4; ++dj) o[qi][dj] = (floatx4){0.f, 0.f, 0.f, 0.f};

    const int nkt = 2 * (qt + 1);   // K-tiles covering [0, q0+QT)
    for (int kt = 0; kt < nkt; ++kt) {
        const int k0 = kt * KT;
        __syncthreads();   // previous tile's LDS reads done
        // ---- stage K/V tile (f32 -> bf16), V transposed ----
        {
            const int key = tid >> 2;
            const int db  = (tid & 3) * 16;
            const float* kp = kv + ((((size_t)b * SK + (k0 + key)) * 2) * HKV + hkv) * D_ + db;
            const float* vp = kp + HKV * D_;
#pragma unroll
            for (int i = 0; i < 16; i += 4) {
                float4 kx = *(const float4*)(kp + i);
                float4 vx = *(const float4*)(vp + i);
                Kt[key][db + i + 0] = (__bf16)kx.x;
                Kt[key][db + i + 1] = (__bf16)kx.y;
                Kt[key][db + i + 2] = (__bf16)kx.z;
                Kt[key][db + i + 3] = (__bf16)kx.w;
                Vt[db + i + 0][key] = (__bf16)vx.x;
                Vt[db + i + 1][key] = (__bf16)vx.y;
                Vt[db + i + 2][key] = (__bf16)vx.z;
                Vt[db + i + 3][key] = (__bf16)vx.w;
            }
            if (tid < KT) padf[tid] = mask[b * SK + k0 + tid] ? 0.f : NEGV;
        }
        __syncthreads();

        // ---- K B-fragments: B[k=d][n=key], lane n=lane&15, k=quad*8+j ----
        bf16x8 bk[4][2];
#pragma unroll
        for (int kj = 0; kj < 4; ++kj)
#pragma unroll
            for (int kc = 0; kc < 2; ++kc)
                bk[kj][kc] = *(const bf16x8*)&Kt[kj * 16 + col][kc * 32 + quad * 8];

        // ---- scores + online softmax per 16-row tile ----
#pragma unroll
        for (int qi = 0; qi < 2; ++qi) {
            floatx4 c[4];
#pragma unroll
            for (int kj = 0; kj < 4; ++kj) {
                c[kj] = (floatx4){0.f, 0.f, 0.f, 0.f};
#pragma unroll
                for (int kc = 0; kc < 2; ++kc)
                    c[kj] = __builtin_amdgcn_mfma_f32_16x16x32_bf16(
                        aq[qi][kc], bk[kj][kc], c[kj], 0, 0, 0);
            }
            const int rowb = qw + qi * 16 + quad * 4;  // + r
#pragma unroll
            for (int kj = 0; kj < 4; ++kj) {
                const int key = k0 + kj * 16 + col;
                const float pf = padf[kj * 16 + col];
#pragma unroll
                for (int r = 0; r < 4; ++r) {
                    float s = c[kj][r] + pf;
                    c[kj][r] = (key > rowb + r) ? NEGV : s;
                }
            }
#pragma unroll
            for (int r = 0; r < 4; ++r) {
                float mx = fmaxf(fmaxf(c[0][r], c[1][r]), fmaxf(c[2][r], c[3][r]));
#pragma unroll
                for (int off = 8; off >= 1; off >>= 1)
                    mx = fmaxf(mx, __shfl_xor(mx, off, 16));
                const float mnew  = fmaxf(m_s[qi][r], mx);
                const float alpha = __expf(m_s[qi][r] - mnew);
                float rs = 0.f;
#pragma unroll
                for (int kj = 0; kj < 4; ++kj) {
                    float p = __expf(c[kj][r] - mnew);
                    c[kj][r] = p;
                    rs += p;
                }
#pragma unroll
                for (int off = 8; off >= 1; off >>= 1)
                    rs += __shfl_xor(rs, off, 16);
                l_s[qi][r] = l_s[qi][r] * alpha + rs;
                m_s[qi][r] = mnew;
#pragma unroll
                for (int dj = 0; dj < 4; ++dj) o[qi][dj][r] *= alpha;
                const int prow = qi * 16 + quad * 4 + r;
#pragma unroll
                for (int kj = 0; kj < 4; ++kj)
                    Pl[wave][prow][kj * 16 + col] = (__bf16)c[kj][r];
            }
        }

        // ---- P @ V : A = P (m=qrow, k=key), B = V (k=key, n=d) ----
        bf16x8 bv[4][2];
#pragma unroll
        for (int dj = 0; dj < 4; ++dj)
#pragma unroll
            for (int kc = 0; kc < 2; ++kc)
                bv[dj][kc] = *(const bf16x8*)&Vt[dj * 16 + col][kc * 32 + quad * 8];
#pragma unroll
        for (int qi = 0; qi < 2; ++qi) {
            bf16x8 ap[2];
#pragma unroll
            for (int kc = 0; kc < 2; ++kc)
                ap[kc] = *(const bf16x8*)&Pl[wave][qi * 16 + col][kc * 32 + quad * 8];
#pragma unroll
            for (int dj = 0; dj < 4; ++dj)
#pragma unroll
                for (int kc = 0; kc < 2; ++kc)
                    o[qi][dj] = __builtin_amdgcn_mfma_f32_16x16x32_bf16(
                        ap[kc], bv[dj][kc], o[qi][dj], 0, 0, 0);
        }
    }

    // ---- epilogue: fold analytic NEG tail, normalize, store ----
    const float tailn = (float)(SK - (q0 + QT));
#pragma unroll
    for (int qi = 0; qi < 2; ++qi) {
#pragma unroll
        for (int r = 0; r < 4; ++r) {
            const float w   = __expf(NEGV - m_s[qi][r]);   // 0 for normal rows
            const float inv = 1.0f / (l_s[qi][r] + w * tailn);
            const int row = qw + qi * 16 + quad * 4 + r;
            float* op = out + (((size_t)b * SQ + row) * H_ + h) * D_ + col;
#pragma unroll
            for (int dj = 0; dj < 4; ++dj)
                op[dj * 16] = (o[qi][dj][r] + w * vtail[dj]) * inv;
        }
    }
}

extern "C" void kernel_launch(void* const* d_in, const int* in_sizes, int n_in,
                              void* d_out, int out_size, void* d_ws, size_t ws_size,
                              hipStream_t stream) {
    const float* q   = (const float*)d_in[0];
    const float* kv  = (const float*)d_in[1];
    const int* mask  = (const int*)d_in[2];
    float* out       = (float*)d_out;
    dim3 grid(SQ / QT, B_ * H_);
    attn_kernel<<<grid, 256, 0, stream>>>(q, kv, mask, out);
}

// Round 2
// 167.430 us; speedup vs baseline: 1.3055x; 1.3055x over previous
//
#include <hip/hip_runtime.h>
#include <math.h>

// CrossAttention B=2, Sq=Sk=2048, H=16, Hkv=4, D=64, fp32 io.
// R2: QT=64 (4 waves x 16 rows), 1024 blocks LPT-ordered, register-prefetch
// software pipeline, packed LDS staging, lazy analytic NEG-tail epilogue.

typedef __bf16 bf16x4 __attribute__((ext_vector_type(4)));
typedef __bf16 bf16x8 __attribute__((ext_vector_type(8)));
typedef float floatx4 __attribute__((ext_vector_type(4)));

#define B_ 2
#define SQ 2048
#define SK 2048
#define H_ 16
#define HKV 4
#define D_ 64
#define QT 64
#define KT 64
#define PADLD 72            // bf16 elems per LDS row: 144B rows, 16B-aligned
#define KVROW 512           // floats per (b,s) slot in kv: 2*HKV*D
#define NEGV (-10000.0f)

__global__ __launch_bounds__(256, 4)
void attn_kernel(const float* __restrict__ q,
                 const float* __restrict__ kv,
                 const int* __restrict__ mask,
                 float* __restrict__ out)
{
    __shared__ alignas(16) __bf16 Kt[KT][PADLD];     // K tile [key][d]
    __shared__ alignas(16) __bf16 Vt[D_][PADLD];     // V tile transposed [d][key]
    __shared__ alignas(16) __bf16 Pl[4][16][PADLD];  // per-wave P [qrow][key]
    __shared__ float padf[KT];

    const int tid  = threadIdx.x;
    const int wave = tid >> 6;
    const int lane = tid & 63;
    const int col  = lane & 15;
    const int quad = lane >> 4;

    const int bh = blockIdx.x;               // all 32 bh of heaviest qt dispatch first
    const int qt = 31 - (int)blockIdx.y;     // LPT: heavy blocks first
    const int b   = bh >> 4;
    const int h   = bh & 15;
    const int hkv = h >> 2;
    const int q0  = qt * QT;
    const int qw  = q0 + wave * 16;          // this wave's first q row

    // ---- Q A-fragments, pre-scaled by 1/sqrt(D) ----
    bf16x8 aq[2];
    {
        const int row = qw + col;
        const float* qp = q + (((size_t)b * SQ + row) * H_ + h) * D_ + quad * 8;
#pragma unroll
        for (int kc = 0; kc < 2; ++kc) {
            const float* p = qp + kc * 32;
#pragma unroll
            for (int j = 0; j < 8; ++j) aq[kc][j] = (__bf16)(p[j] * 0.125f);
        }
    }

    float m_s[4], l_s[4];
    floatx4 o[4];
#pragma unroll
    for (int r = 0; r < 4; ++r) { m_s[r] = -1e30f; l_s[r] = 0.f; }
#pragma unroll
    for (int dj = 0; dj < 4; ++dj) o[dj] = (floatx4){0.f, 0.f, 0.f, 0.f};

    // staging thread mappings
    const int kkey = tid >> 4;          // K: rows kkey+16i, 4 d at kd (coalesced global)
    const int kd   = (tid & 15) * 4;
    const int vkey = (tid & 15) * 4;    // V: keys vkey..vkey+3, 4 d at vd (clean LDS banks)
    const int vd   = (tid >> 4) * 4;

    const float* kvb = kv + (size_t)b * SK * KVROW + hkv * D_;

    float4 kreg[4], vreg[4];
    int mreg = 0;

    auto prefetch = [&](int kt) {
        const float* kb = kvb + (size_t)kt * KT * KVROW;
#pragma unroll
        for (int i = 0; i < 4; ++i)
            kreg[i] = *(const float4*)(kb + (kkey + 16 * i) * KVROW + kd);
        const float* vb = kb + HKV * D_;
#pragma unroll
        for (int i = 0; i < 4; ++i)
            vreg[i] = *(const float4*)(vb + (vkey + i) * KVROW + vd);
        if (tid < KT) mreg = mask[b * SK + kt * KT + tid];
    };

    auto stage = [&]() {
#pragma unroll
        for (int i = 0; i < 4; ++i) {
            bf16x4 t = { (__bf16)kreg[i].x, (__bf16)kreg[i].y,
                         (__bf16)kreg[i].z, (__bf16)kreg[i].w };
            *(bf16x4*)&Kt[kkey + 16 * i][kd] = t;
        }
        const float* vf = (const float*)vreg;   // vf[i*4+j] = V[vkey+i][vd+j]
#pragma unroll
        for (int j = 0; j < 4; ++j) {
            bf16x4 t = { (__bf16)vf[0 * 4 + j], (__bf16)vf[1 * 4 + j],
                         (__bf16)vf[2 * 4 + j], (__bf16)vf[3 * 4 + j] };
            *(bf16x4*)&Vt[vd + j][vkey] = t;
        }
        if (tid < KT) padf[tid] = mreg ? 0.f : NEGV;
    };

    const int nkt = qt + 1;   // K-tiles covering [0, q0+QT)
    prefetch(0);

    for (int kt = 0; kt < nkt; ++kt) {
        stage();
        __syncthreads();
        if (kt + 1 < nkt) prefetch(kt + 1);   // overlaps with compute below

        // ---- QK^T ----
        floatx4 c[4];
#pragma unroll
        for (int kj = 0; kj < 4; ++kj) {
            c[kj] = (floatx4){0.f, 0.f, 0.f, 0.f};
#pragma unroll
            for (int kc = 0; kc < 2; ++kc) {
                bf16x8 bk = *(const bf16x8*)&Kt[kj * 16 + col][kc * 32 + quad * 8];
                c[kj] = __builtin_amdgcn_mfma_f32_16x16x32_bf16(aq[kc], bk, c[kj], 0, 0, 0);
            }
        }
        // ---- masks ----
#pragma unroll
        for (int kj = 0; kj < 4; ++kj) {
            const float pf = padf[kj * 16 + col];
#pragma unroll
            for (int r = 0; r < 4; ++r) c[kj][r] += pf;
        }
        if (kt == qt) {   // only the diagonal tile needs the causal mask
            const int rowl = wave * 16 + quad * 4;
#pragma unroll
            for (int kj = 0; kj < 4; ++kj) {
                const int keyl = kj * 16 + col;
#pragma unroll
                for (int r = 0; r < 4; ++r)
                    if (keyl > rowl + r) c[kj][r] = NEGV;
            }
        }
        // ---- online softmax (4 independent row-chains for ILP) ----
#pragma unroll
        for (int r = 0; r < 4; ++r) {
            float mx = fmaxf(fmaxf(c[0][r], c[1][r]), fmaxf(c[2][r], c[3][r]));
#pragma unroll
            for (int off = 8; off >= 1; off >>= 1)
                mx = fmaxf(mx, __shfl_xor(mx, off, 16));
            const float mnew  = fmaxf(m_s[r], mx);
            const float alpha = __expf(m_s[r] - mnew);
            float rs = 0.f;
#pragma unroll
            for (int kj = 0; kj < 4; ++kj) {
                float p = __expf(c[kj][r] - mnew);
                c[kj][r] = p;
                rs += p;
            }
#pragma unroll
            for (int off = 8; off >= 1; off >>= 1)
                rs += __shfl_xor(rs, off, 16);
            l_s[r] = l_s[r] * alpha + rs;
            m_s[r] = mnew;
#pragma unroll
            for (int dj = 0; dj < 4; ++dj) o[dj][r] *= alpha;
            const int prow = quad * 4 + r;
#pragma unroll
            for (int kj = 0; kj < 4; ++kj)
                Pl[wave][prow][kj * 16 + col] = (__bf16)c[kj][r];
        }
        // ---- P @ V (P round-trip is wave-private: no barrier needed) ----
        bf16x8 ap[2];
#pragma unroll
        for (int kc = 0; kc < 2; ++kc)
            ap[kc] = *(const bf16x8*)&Pl[wave][col][kc * 32 + quad * 8];
#pragma unroll
        for (int dj = 0; dj < 4; ++dj)
#pragma unroll
            for (int kc = 0; kc < 2; ++kc) {
                bf16x8 bv = *(const bf16x8*)&Vt[dj * 16 + col][kc * 32 + quad * 8];
                o[dj] = __builtin_amdgcn_mfma_f32_16x16x32_bf16(ap[kc], bv, o[dj], 0, 0, 0);
            }
        __syncthreads();   // all waves done with LDS before next stage overwrites
    }

    // ---- epilogue: lazy analytic NEG-tail, normalize, store ----
    bool need = false;
#pragma unroll
    for (int r = 0; r < 4; ++r) need = need || (m_s[r] < -9900.f);
    floatx4 vtail = (floatx4){0.f, 0.f, 0.f, 0.f};
    if (__ballot(need)) {   // only fully-padded-visible rows (rare, light blocks)
        for (int s = q0 + QT + quad; s < SK; s += 4) {
            const float* vp = kvb + (size_t)s * KVROW + HKV * D_;
#pragma unroll
            for (int dj = 0; dj < 4; ++dj) vtail[dj] += vp[dj * 16 + col];
        }
#pragma unroll
        for (int dj = 0; dj < 4; ++dj) {
            float v = vtail[dj];
            v += __shfl_xor(v, 16, 64);
            v += __shfl_xor(v, 32, 64);
            vtail[dj] = v;
        }
    }
    const float tailn = (float)(SK - (q0 + QT));
#pragma unroll
    for (int r = 0; r < 4; ++r) {
        const float w   = __expf(NEGV - m_s[r]);   // exactly 0 for normal rows
        const float inv = 1.0f / (l_s[r] + w * tailn);
        const int row = qw + quad * 4 + r;
        float* op = out + (((size_t)b * SQ + row) * H_ + h) * D_ + col;
#pragma unroll
        for (int dj = 0; dj < 4; ++dj)
            op[dj * 16] = (o[dj][r] + w * vtail[dj]) * inv;
    }
}

extern "C" void kernel_launch(void* const* d_in, const int* in_sizes, int n_in,
                              void* d_out, int out_size, void* d_ws, size_t ws_size,
                              hipStream_t stream) {
    const float* q   = (const float*)d_in[0];
    const float* kv  = (const float*)d_in[1];
    const int* mask  = (const int*)d_in[2];
    float* out       = (float*)d_out;
    dim3 grid(B_ * H_, SQ / QT);   // x = bh (fastest), y = reversed q-tile
    attn_kernel<<<grid, 256, 0, stream>>>(q, kv, mask, out);
}